// Round 11
// baseline (9686.518 us; speedup 1.0000x reference)
//
#include <hip/hip_runtime.h>
#include <hip/hip_bf16.h>

// BiLSTM-CRF tagger, MI355X. Round 11: revert to R9 barrier-gated protocol
// (R10's barrier-free free-run polls regressed: +80MB MALL traffic), and
// halve participants: 24 blocks/dir, 2 h-elems per wave, bf16 Whh in regs.
//   K2 fused embed-gather + xg GEMM, 128x128 tile (bf16 out)
//   K3 LSTM recurrence: 48 blocks (24/dir) x 1024 thr; wave wv owns
//      jA=slot*32+wv, jB=jA+16. msg u32 {tag u16|bf16 h}, parity dbuf,
//      dual pollers w/ selective re-read, 2 barriers/step, abort cascade.
//   K4 head + log_softmax, Wc staged in LDS -> K5 wave-sync Viterbi.

#define SEQ  2048
#define DINW 496
#define HDIM 768
#define G4   3072
#define CDIM 13
#define NWG  24           // workgroups per direction (2*NWG = 48 blocks)
#define JPW  32           // h elements per workgroup (two per wave)
#define DATA_SPIN (1u << 14)

__device__ __forceinline__ float sigf(float x) { return 1.0f / (1.0f + __expf(-x)); }
__device__ __forceinline__ float tanhf_fast(float x) {
    float ax = fabsf(x);
    float e  = __expf(-2.0f * ax);
    float t  = (1.0f - e) / (1.0f + e);
    return copysignf(t, x);
}
__device__ __forceinline__ unsigned pack_bf16(float a, float b) {
    union { __hip_bfloat16 h; unsigned short u; } x, y;
    x.h = __float2bfloat16(a); y.h = __float2bfloat16(b);
    return (unsigned)x.u | ((unsigned)y.u << 16);
}

// ---- K2: xg = [we[x],ce[casing],pe[pos]] @ Wih^T + b  (bf16 out), 128x128 tile
__global__ __launch_bounds__(256) void k_gemm_xg(
    const int* __restrict__ x, const int* __restrict__ casing, const int* __restrict__ pos,
    const float* __restrict__ we, const float* __restrict__ ce, const float* __restrict__ pe,
    const float* __restrict__ Wih_f, const float* __restrict__ b_f,
    const float* __restrict__ Wih_b, const float* __restrict__ b_b,
    __hip_bfloat16* __restrict__ xg_f, __hip_bfloat16* __restrict__ xg_b)
{
    __shared__ float As[16][132];
    __shared__ float Bs[16][132];
    int dir = blockIdx.z;
    const float* B    = dir ? Wih_b : Wih_f;
    const float* bias = dir ? b_b   : b_f;
    __hip_bfloat16* C = dir ? xg_b  : xg_f;
    int n0 = blockIdx.x * 128, m0 = blockIdx.y * 128;
    int tid = threadIdx.x;
    int r  = tid >> 1, cb = (tid & 1) * 8;
    int tx = tid & 15, ty = tid >> 4;

    int m = m0 + r;
    const float* arow_w = we + (size_t)x[m] * 400;
    const float* arow_c = ce + (size_t)casing[m] * 32;
    const float* arow_p = pe + (size_t)pos[m] * 64;
    const float* brow   = B + (size_t)(n0 + r) * DINW;

    float acc[8][8] = {};
    for (int k0 = 0; k0 < DINW; k0 += 16) {
        int c0 = k0 + cb;
        float4 a0, a1, b0, b1;
        if (c0 < 400)      a0 = *(const float4*)(arow_w + c0);
        else if (c0 < 432) a0 = *(const float4*)(arow_c + (c0 - 400));
        else               a0 = *(const float4*)(arow_p + (c0 - 432));
        int c4 = c0 + 4;
        if (c4 < 400)      a1 = *(const float4*)(arow_w + c4);
        else if (c4 < 432) a1 = *(const float4*)(arow_c + (c4 - 400));
        else               a1 = *(const float4*)(arow_p + (c4 - 432));
        b0 = *(const float4*)(brow + c0);
        b1 = *(const float4*)(brow + c4);
        __syncthreads();
        As[cb + 0][r] = a0.x; As[cb + 1][r] = a0.y; As[cb + 2][r] = a0.z; As[cb + 3][r] = a0.w;
        As[cb + 4][r] = a1.x; As[cb + 5][r] = a1.y; As[cb + 6][r] = a1.z; As[cb + 7][r] = a1.w;
        Bs[cb + 0][r] = b0.x; Bs[cb + 1][r] = b0.y; Bs[cb + 2][r] = b0.z; Bs[cb + 3][r] = b0.w;
        Bs[cb + 4][r] = b1.x; Bs[cb + 5][r] = b1.y; Bs[cb + 6][r] = b1.z; Bs[cb + 7][r] = b1.w;
        __syncthreads();
        #pragma unroll
        for (int k = 0; k < 16; k++) {
            float4 av0 = *(const float4*)&As[k][ty * 8];
            float4 av1 = *(const float4*)&As[k][ty * 8 + 4];
            float4 bv0 = *(const float4*)&Bs[k][tx * 8];
            float4 bv1 = *(const float4*)&Bs[k][tx * 8 + 4];
            float aa[8] = {av0.x, av0.y, av0.z, av0.w, av1.x, av1.y, av1.z, av1.w};
            float bb[8] = {bv0.x, bv0.y, bv0.z, bv0.w, bv1.x, bv1.y, bv1.z, bv1.w};
            #pragma unroll
            for (int i = 0; i < 8; i++)
                #pragma unroll
                for (int jj = 0; jj < 8; jj++)
                    acc[i][jj] += aa[i] * bb[jj];
        }
    }
    float4 bs0 = *(const float4*)(bias + n0 + tx * 8);
    float4 bs1 = *(const float4*)(bias + n0 + tx * 8 + 4);
    float bb8[8] = {bs0.x, bs0.y, bs0.z, bs0.w, bs1.x, bs1.y, bs1.z, bs1.w};
    #pragma unroll
    for (int i = 0; i < 8; i++) {
        int row = m0 + ty * 8 + i;
        union { __hip_bfloat16 h[4]; ushort4 u; } c0v, c1v;
        #pragma unroll
        for (int jj = 0; jj < 4; jj++) {
            c0v.h[jj] = __float2bfloat16(acc[i][jj] + bb8[jj]);
            c1v.h[jj] = __float2bfloat16(acc[i][jj + 4] + bb8[jj + 4]);
        }
        *(ushort4*)(C + (size_t)row * G4 + n0 + tx * 8)     = c0v.u;
        *(ushort4*)(C + (size_t)row * G4 + n0 + tx * 8 + 4) = c1v.u;
    }
}

// ------------------------------------------------------- K3: LSTM recurrence
// R9 protocol (proven): msg[dir][parity][768] u32 {tag<<16 | bf16bits(h)};
// h(t) -> parity t&1, tag t+1. Consumer step t polls parity (t&1)^1 for
// tag == t (selective re-reads, waves 0&1 split halves). 2 barriers/step.
// All-to-all gate (deadlock/overwrite-free): a block emits tag t+2 only after
// passing step-t+1's B1, i.e. after consuming ALL tag-(t+1) words; those exist
// only after every block consumed tag t. Each wave owns TWO h-elems (jA,jB);
// Whh held as packed bf16 pairs in 48 VGPRs/lane.
__global__ __launch_bounds__(1024) void k_lstm(
    const __hip_bfloat16* __restrict__ xg_f, const __hip_bfloat16* __restrict__ xg_b,
    const float* __restrict__ Whh_f, const float* __restrict__ Whh_b,
    const float* __restrict__ h0, const float* __restrict__ c0v,
    float* __restrict__ hs_f, float* __restrict__ hs_b,
    unsigned* __restrict__ msg, unsigned* __restrict__ abortw)
{
    __shared__ float hbuf[2][HDIM];
    __shared__ unsigned sdead;

    int wg = blockIdx.x;
    int dir = wg & 1, slot = wg >> 1;          // slot 0..23
    const __hip_bfloat16* xg = dir ? xg_b : xg_f;
    const float* Whh = dir ? Whh_b : Whh_f;
    float* hs        = dir ? hs_b  : hs_f;
    unsigned* mdir = msg + (size_t)dir * 2 * HDIM;

    int tid = threadIdx.x, lane = tid & 63, wv = tid >> 6;   // wv 0..15
    int q = lane >> 4, gl = lane & 15;
    int jA = slot * JPW + wv;        // first h element
    int jB = jA + 16;                // second h element

    // packed bf16 weights: rows q*768+jA / q*768+jB, cols gl*4 + m*64 (+e)
    unsigned wA[24], wB[24];
    {
        const float* wrA = Whh + (size_t)(q * HDIM + jA) * HDIM;
        const float* wrB = Whh + (size_t)(q * HDIM + jB) * HDIM;
        #pragma unroll
        for (int m = 0; m < 12; m++) {
            float4 a = *(const float4*)(wrA + gl * 4 + m * 64);
            float4 b = *(const float4*)(wrB + gl * 4 + m * 64);
            wA[m * 2 + 0] = pack_bf16(a.x, a.y);
            wA[m * 2 + 1] = pack_bf16(a.z, a.w);
            wB[m * 2 + 0] = pack_bf16(b.x, b.y);
            wB[m * 2 + 1] = pack_bf16(b.z, b.w);
        }
    }
    float cstA = c0v[dir * HDIM + jA];
    float cstB = c0v[dir * HDIM + jB];

    if (tid == 0) sdead = 0;

    for (int t = 0; t < SEQ; t++) {
        int xrow = dir ? (SEQ - 1 - t) : t;
        const __hip_bfloat16* xgaA = xg + (size_t)xrow * G4 + jA;
        const __hip_bfloat16* xgaB = xg + (size_t)xrow * G4 + jB;
        float xvA0 = __bfloat162float(xgaA[0]);
        float xvA1 = __bfloat162float(xgaA[HDIM]);
        float xvA2 = __bfloat162float(xgaA[2 * HDIM]);
        float xvA3 = __bfloat162float(xgaA[3 * HDIM]);
        float xvB0 = __bfloat162float(xgaB[0]);
        float xvB1 = __bfloat162float(xgaB[HDIM]);
        float xvB2 = __bfloat162float(xgaB[2 * HDIM]);
        float xvB3 = __bfloat162float(xgaB[3 * HDIM]);

        int par = (t & 1) ^ 1;   // parity slot holding h(t-1)

        if (wv < 2) {            // dual pollers: wave0 words 0..383, wave1 384..767
            int base = wv * 6;
            if (t == 0) {
                #pragma unroll
                for (int m = 0; m < 6; m++)
                    hbuf[1][(base + m) * 64 + lane] = h0[dir * HDIM + (base + m) * 64 + lane];
            } else {
                const unsigned* g = mdir + (size_t)par * HDIM;
                unsigned vals[6];
                unsigned fresh = 0, rounds = 0;
                bool dead = false;
                for (;;) {
                    #pragma unroll
                    for (int m = 0; m < 6; m++)
                        if (!(fresh & (1u << m)))
                            vals[m] = __hip_atomic_load(&g[(base + m) * 64 + lane],
                                        __ATOMIC_RELAXED, __HIP_MEMORY_SCOPE_AGENT);
                    #pragma unroll
                    for (int m = 0; m < 6; m++)
                        if ((vals[m] >> 16) == (unsigned)t) fresh |= (1u << m);
                    if (__all(fresh == 0x3Fu)) break;
                    unsigned ab = __hip_atomic_load(abortw,
                                    __ATOMIC_RELAXED, __HIP_MEMORY_SCOPE_AGENT);
                    if (ab || ++rounds >= DATA_SPIN) { dead = true; break; }
                }
                #pragma unroll
                for (int m = 0; m < 6; m++) {
                    union { unsigned u; float f; } cvt;
                    cvt.u = (vals[m] & 0xFFFFu) << 16;   // bf16 -> f32 (exact)
                    hbuf[par][(base + m) * 64 + lane] = cvt.f;
                }
                if (dead && lane == 0) {   // cascade shutdown, bounded everywhere
                    __hip_atomic_store(abortw, 1u,
                                       __ATOMIC_RELAXED, __HIP_MEMORY_SCOPE_AGENT);
                    sdead = 1;
                }
            }
        }

        __syncthreads();           // B1: hbuf ready (and sdead visible)
        if (sdead) break;          // block-uniform bail

        // two matvec slices over this lane's 48 columns from LDS
        float accA = 0.f, accB = 0.f;
        #pragma unroll
        for (int m = 0; m < 12; m++) {
            float4 f4 = *(const float4*)&hbuf[par][gl * 4 + m * 64];
            unsigned a0 = wA[m * 2], a1 = wA[m * 2 + 1];
            unsigned b0 = wB[m * 2], b1 = wB[m * 2 + 1];
            accA += __uint_as_float(a0 << 16)          * f4.x
                  + __uint_as_float(a0 & 0xFFFF0000u)  * f4.y
                  + __uint_as_float(a1 << 16)          * f4.z
                  + __uint_as_float(a1 & 0xFFFF0000u)  * f4.w;
            accB += __uint_as_float(b0 << 16)          * f4.x
                  + __uint_as_float(b0 & 0xFFFF0000u)  * f4.y
                  + __uint_as_float(b1 << 16)          * f4.z
                  + __uint_as_float(b1 & 0xFFFF0000u)  * f4.w;
        }
        #pragma unroll
        for (int d = 1; d < 16; d <<= 1) {
            accA += __shfl_xor(accA, d);
            accB += __shfl_xor(accB, d);
        }
        float siA = __shfl(accA, 0),  sfA = __shfl(accA, 16);
        float sgA = __shfl(accA, 32), soA = __shfl(accA, 48);
        float siB = __shfl(accB, 0),  sfB = __shfl(accB, 16);
        float sgB = __shfl(accB, 32), soB = __shfl(accB, 48);

        float giA = sigf(xvA0 + siA), gfA = sigf(xvA1 + sfA);
        float ggA = tanhf_fast(xvA2 + sgA), goA = sigf(xvA3 + soA);
        cstA = gfA * cstA + giA * ggA;
        float hA = goA * tanhf_fast(cstA);

        float giB = sigf(xvB0 + siB), gfB = sigf(xvB1 + sfB);
        float ggB = tanhf_fast(xvB2 + sgB), goB = sigf(xvB3 + soB);
        cstB = gfB * cstB + giB * ggB;
        float hB = goB * tanhf_fast(cstB);

        if (lane == 0) {
            union { __hip_bfloat16 b; unsigned short u; } cvA, cvB;
            cvA.b = __float2bfloat16(hA);
            cvB.b = __float2bfloat16(hB);
            unsigned wordA = ((unsigned)(t + 1) << 16) | (unsigned)cvA.u;
            unsigned wordB = ((unsigned)(t + 1) << 16) | (unsigned)cvB.u;
            __hip_atomic_store(&mdir[(size_t)(t & 1) * HDIM + jA], wordA,
                               __ATOMIC_RELAXED, __HIP_MEMORY_SCOPE_AGENT);  // msg first!
            __hip_atomic_store(&mdir[(size_t)(t & 1) * HDIM + jB], wordB,
                               __ATOMIC_RELAXED, __HIP_MEMORY_SCOPE_AGENT);
            int hrow = dir ? (SEQ - 1 - t) : t;
            hs[(size_t)hrow * HDIM + jA] = hA;        // for K4 (cross-dispatch)
            hs[(size_t)hrow * HDIM + jB] = hB;
        }
        __syncthreads();           // B2: bounds wave skew; protects hbuf reuse
    }
}

// ---- K4: o = [hs_f,hs_b]@Wc^T + bc, log_softmax; Wc staged in LDS, 16 rows/blk
__global__ __launch_bounds__(256) void k_head(
    const float* __restrict__ hs_f, const float* __restrict__ hs_b,
    const float* __restrict__ Wc, const float* __restrict__ bc,
    float* __restrict__ out)
{
    __shared__ float wcs[CDIM][1536];
    __shared__ float bcs[CDIM];
    int tid = threadIdx.x;
    for (int i = tid; i < CDIM * 1536; i += 256) {
        int n = i / 1536;
        wcs[n][i - n * 1536] = Wc[i];
    }
    if (tid < CDIM) bcs[tid] = bc[tid];
    __syncthreads();

    int lane = tid & 63, wv = tid >> 6;
    int off = (lane < 32) ? lane * 24 : 768 + (lane - 32) * 24;
    for (int rr = 0; rr < 4; rr++) {
        int row = blockIdx.x * 16 + wv * 4 + rr;
        const float* src = (lane < 32) ? (hs_f + (size_t)row * HDIM + lane * 24)
                                       : (hs_b + (size_t)row * HDIM + (lane - 32) * 24);
        float hvv[24];
        #pragma unroll
        for (int k = 0; k < 6; k++) {
            float4 f4 = *(const float4*)(src + k * 4);
            hvv[k * 4 + 0] = f4.x; hvv[k * 4 + 1] = f4.y;
            hvv[k * 4 + 2] = f4.z; hvv[k * 4 + 3] = f4.w;
        }
        float o[CDIM];
        #pragma unroll
        for (int n = 0; n < CDIM; n++) {
            const float* wr2 = &wcs[n][off];
            float s0 = 0.f, s1 = 0.f, s2 = 0.f, s3 = 0.f;
            #pragma unroll
            for (int k = 0; k < 6; k++) {
                float4 w4 = *(const float4*)(wr2 + k * 4);
                s0 += w4.x * hvv[k * 4 + 0];
                s1 += w4.y * hvv[k * 4 + 1];
                s2 += w4.z * hvv[k * 4 + 2];
                s3 += w4.w * hvv[k * 4 + 3];
            }
            o[n] = (s0 + s1) + (s2 + s3);
        }
        #pragma unroll
        for (int n = 0; n < CDIM; n++) {
            #pragma unroll
            for (int d = 1; d < 64; d <<= 1) o[n] += __shfl_xor(o[n], d);
            o[n] += bcs[n];
        }
        float m = o[0];
        #pragma unroll
        for (int n = 1; n < CDIM; n++) m = fmaxf(m, o[n]);
        float sum = 0.f;
        #pragma unroll
        for (int n = 0; n < CDIM; n++) sum += __expf(o[n] - m);
        float ls = m + __logf(sum);
        if (lane == 0) {
            #pragma unroll
            for (int n = 0; n < CDIM; n++) out[(size_t)row * CDIM + n] = o[n] - ls;
        }
    }
}

// ------------------------------------ K5: Viterbi, single wave, shuffle-based
__global__ __launch_bounds__(64) void k_viterbi(
    const float* __restrict__ ts, const float* __restrict__ st,
    const float* __restrict__ en, const float* __restrict__ tr,
    float* __restrict__ tags_out)
{
    __shared__ unsigned char bp[SEQ - 1][16];
    __shared__ unsigned char path[SEQ];
    int n = threadIdx.x;
    bool act = n < CDIM;
    float trn[CDIM];
    #pragma unroll
    for (int p = 0; p < CDIM; p++) trn[p] = act ? tr[p * CDIM + n] : -1e30f;
    float score = act ? (st[n] + ts[n]) : -1e30f;

    for (int s = 1; s < SEQ; s++) {
        float em = act ? ts[(size_t)s * CDIM + n] : 0.f;
        float sp[CDIM];
        #pragma unroll
        for (int p = 0; p < CDIM; p++) sp[p] = __shfl(score, p);
        float best = -1e30f; int arg = 0;
        #pragma unroll
        for (int p = 0; p < CDIM; p++) {
            float v = sp[p] + trn[p];
            if (v > best) { best = v; arg = p; }   // strict > keeps FIRST max
        }
        score = best + em;
        if (act) bp[s - 1][n] = (unsigned char)arg;
    }
    float fin = act ? (score + en[n]) : -1e30f;
    float fv[CDIM];
    #pragma unroll
    for (int p = 0; p < CDIM; p++) fv[p] = __shfl(fin, p);
    __syncthreads();
    if (n == 0) {
        float best = -1e30f; int last = 0;
        #pragma unroll
        for (int p = 0; p < CDIM; p++) { if (fv[p] > best) { best = fv[p]; last = p; } }
        int cur = last;
        path[SEQ - 1] = (unsigned char)cur;
        for (int s = SEQ - 2; s >= 0; s--) { cur = bp[s][cur]; path[s] = (unsigned char)cur; }
    }
    __syncthreads();
    for (int i = n; i < SEQ; i += 64) tags_out[i] = (float)path[i];
}

// --------------------------------------------- fallback if ws is too small
__global__ void k_zero(float* p, int n) {
    int i = blockIdx.x * 256 + threadIdx.x;
    if (i < n) p[i] = 0.f;
}

// ----------------------------------------------------------------- launch
extern "C" void kernel_launch(void* const* d_in, const int* in_sizes, int n_in,
                              void* d_out, int out_size, void* d_ws, size_t ws_size,
                              hipStream_t stream)
{
    const int*   x      = (const int*)d_in[0];
    const int*   casing = (const int*)d_in[1];
    const int*   pos    = (const int*)d_in[2];
    const float* we     = (const float*)d_in[3];
    const float* ce     = (const float*)d_in[4];
    const float* pe     = (const float*)d_in[5];
    const float* Wih_f  = (const float*)d_in[6];
    const float* Whh_f  = (const float*)d_in[7];
    const float* b_f    = (const float*)d_in[8];
    const float* Wih_b  = (const float*)d_in[9];
    const float* Whh_b  = (const float*)d_in[10];
    const float* b_b    = (const float*)d_in[11];
    const float* Wc     = (const float*)d_in[12];
    const float* bc     = (const float*)d_in[13];
    const float* strt   = (const float*)d_in[14];
    const float* endt   = (const float*)d_in[15];
    const float* trans  = (const float*)d_in[16];
    const float* h0     = (const float*)d_in[17];
    const float* c0     = (const float*)d_in[18];

    // ws layout (bytes):
    //   hs_f fp32 6,291,456 @ 0
    //   hs_b fp32 6,291,456 @ 6,291,456
    //   xg_f bf16 12,582,912 @ 12,582,912
    //   xg_b bf16 12,582,912 @ 25,165,824
    //   msg  u32  12,288     @ 37,748,736
    //   abort u32 4          @ 37,761,024
    const size_t need = 37761028;
    if (ws_size < need) {   // clean deterministic failure instead of OOB fault
        k_zero<<<(out_size + 255) / 256, 256, 0, stream>>>((float*)d_out, out_size);
        return;
    }
    char* wsb = (char*)d_ws;
    float* hs_f = (float*)(wsb);
    float* hs_b = (float*)(wsb + 6291456);
    __hip_bfloat16* xg_f = (__hip_bfloat16*)(wsb + 12582912);
    __hip_bfloat16* xg_b = (__hip_bfloat16*)(wsb + 25165824);
    unsigned* msg = (unsigned*)(wsb + 37748736);
    unsigned* abortw = (unsigned*)(wsb + 37761024);

    hipMemsetAsync(msg, 0, 12288 + 4, stream);   // reset tags + abort (replay-safe)

    k_gemm_xg<<<dim3(G4 / 128, SEQ / 128, 2), 256, 0, stream>>>(
        x, casing, pos, we, ce, pe, Wih_f, b_f, Wih_b, b_b, xg_f, xg_b);
    k_lstm<<<2 * NWG, 1024, 0, stream>>>(
        xg_f, xg_b, Whh_f, Whh_b, h0, c0, hs_f, hs_b, msg, abortw);
    k_head<<<SEQ / 16, 256, 0, stream>>>(hs_f, hs_b, Wc, bc, (float*)d_out);
    k_viterbi<<<1, 64, 0, stream>>>(
        (const float*)d_out, strt, endt, trans, (float*)d_out + (size_t)SEQ * CDIM);
}

// Round 12
// 6110.855 us; speedup vs baseline: 1.5851x; 1.5851x over previous
//
#include <hip/hip_runtime.h>
#include <hip/hip_bf16.h>

// BiLSTM-CRF tagger, MI355X. Round 12: R9 protocol + COALESCED line stores.
//   K2 fused embed-gather + xg GEMM, 128x128 tile (bf16 out)
//   K3 LSTM recurrence: 96 blocks (48/dir) x 1024 thr, 1 h-elem/wave (R9
//      geometry, proven 2.52us/step). Change vs R9: per-step msg stores are
//      gathered in LDS and issued after B2 by wave 0 lanes 0..15 as ONE
//      coalesced 64B line store per block (48 store transactions/dir/step
//      instead of 768 scattered 4B stores). Tags per word unchanged ->
//      selective re-read correctness identical; all-to-all gate identical.
//   K4 head + log_softmax, Wc staged in LDS -> K5 wave-sync Viterbi.

#define SEQ  2048
#define DINW 496
#define HDIM 768
#define G4   3072
#define CDIM 13
#define NWG  48           // workgroups per direction (2*NWG = 96 blocks)
#define JPW  16           // h elements per workgroup (one per wave)
#define DATA_SPIN (1u << 14)

__device__ __forceinline__ float sigf(float x) { return 1.0f / (1.0f + __expf(-x)); }
__device__ __forceinline__ float tanhf_fast(float x) {
    float ax = fabsf(x);
    float e  = __expf(-2.0f * ax);
    float t  = (1.0f - e) / (1.0f + e);
    return copysignf(t, x);
}

// ---- K2: xg = [we[x],ce[casing],pe[pos]] @ Wih^T + b  (bf16 out), 128x128 tile
__global__ __launch_bounds__(256) void k_gemm_xg(
    const int* __restrict__ x, const int* __restrict__ casing, const int* __restrict__ pos,
    const float* __restrict__ we, const float* __restrict__ ce, const float* __restrict__ pe,
    const float* __restrict__ Wih_f, const float* __restrict__ b_f,
    const float* __restrict__ Wih_b, const float* __restrict__ b_b,
    __hip_bfloat16* __restrict__ xg_f, __hip_bfloat16* __restrict__ xg_b)
{
    __shared__ float As[16][132];
    __shared__ float Bs[16][132];
    int dir = blockIdx.z;
    const float* B    = dir ? Wih_b : Wih_f;
    const float* bias = dir ? b_b   : b_f;
    __hip_bfloat16* C = dir ? xg_b  : xg_f;
    int n0 = blockIdx.x * 128, m0 = blockIdx.y * 128;
    int tid = threadIdx.x;
    int r  = tid >> 1, cb = (tid & 1) * 8;
    int tx = tid & 15, ty = tid >> 4;

    int m = m0 + r;
    const float* arow_w = we + (size_t)x[m] * 400;
    const float* arow_c = ce + (size_t)casing[m] * 32;
    const float* arow_p = pe + (size_t)pos[m] * 64;
    const float* brow   = B + (size_t)(n0 + r) * DINW;

    float acc[8][8] = {};
    for (int k0 = 0; k0 < DINW; k0 += 16) {
        int c0 = k0 + cb;
        float4 a0, a1, b0, b1;
        if (c0 < 400)      a0 = *(const float4*)(arow_w + c0);
        else if (c0 < 432) a0 = *(const float4*)(arow_c + (c0 - 400));
        else               a0 = *(const float4*)(arow_p + (c0 - 432));
        int c4 = c0 + 4;
        if (c4 < 400)      a1 = *(const float4*)(arow_w + c4);
        else if (c4 < 432) a1 = *(const float4*)(arow_c + (c4 - 400));
        else               a1 = *(const float4*)(arow_p + (c4 - 432));
        b0 = *(const float4*)(brow + c0);
        b1 = *(const float4*)(brow + c4);
        __syncthreads();
        As[cb + 0][r] = a0.x; As[cb + 1][r] = a0.y; As[cb + 2][r] = a0.z; As[cb + 3][r] = a0.w;
        As[cb + 4][r] = a1.x; As[cb + 5][r] = a1.y; As[cb + 6][r] = a1.z; As[cb + 7][r] = a1.w;
        Bs[cb + 0][r] = b0.x; Bs[cb + 1][r] = b0.y; Bs[cb + 2][r] = b0.z; Bs[cb + 3][r] = b0.w;
        Bs[cb + 4][r] = b1.x; Bs[cb + 5][r] = b1.y; Bs[cb + 6][r] = b1.z; Bs[cb + 7][r] = b1.w;
        __syncthreads();
        #pragma unroll
        for (int k = 0; k < 16; k++) {
            float4 av0 = *(const float4*)&As[k][ty * 8];
            float4 av1 = *(const float4*)&As[k][ty * 8 + 4];
            float4 bv0 = *(const float4*)&Bs[k][tx * 8];
            float4 bv1 = *(const float4*)&Bs[k][tx * 8 + 4];
            float aa[8] = {av0.x, av0.y, av0.z, av0.w, av1.x, av1.y, av1.z, av1.w};
            float bb[8] = {bv0.x, bv0.y, bv0.z, bv0.w, bv1.x, bv1.y, bv1.z, bv1.w};
            #pragma unroll
            for (int i = 0; i < 8; i++)
                #pragma unroll
                for (int jj = 0; jj < 8; jj++)
                    acc[i][jj] += aa[i] * bb[jj];
        }
    }
    float4 bs0 = *(const float4*)(bias + n0 + tx * 8);
    float4 bs1 = *(const float4*)(bias + n0 + tx * 8 + 4);
    float bb8[8] = {bs0.x, bs0.y, bs0.z, bs0.w, bs1.x, bs1.y, bs1.z, bs1.w};
    #pragma unroll
    for (int i = 0; i < 8; i++) {
        int row = m0 + ty * 8 + i;
        union { __hip_bfloat16 h[4]; ushort4 u; } c0v, c1v;
        #pragma unroll
        for (int jj = 0; jj < 4; jj++) {
            c0v.h[jj] = __float2bfloat16(acc[i][jj] + bb8[jj]);
            c1v.h[jj] = __float2bfloat16(acc[i][jj + 4] + bb8[jj + 4]);
        }
        *(ushort4*)(C + (size_t)row * G4 + n0 + tx * 8)     = c0v.u;
        *(ushort4*)(C + (size_t)row * G4 + n0 + tx * 8 + 4) = c1v.u;
    }
}

// ------------------------------------------------------- K3: LSTM recurrence
// msg[dir][parity][768] u32 {tag<<16 | bf16bits(h)}: h(t) -> parity t&1, tag
// t+1. Word j = slot*16+wv: each block owns one contiguous 64B line. Stores
// are gathered in LDS during the step and issued AFTER B2 by wave 0 lanes
// 0..15 as a single coalesced line-store transaction. Consumer step t polls
// parity (t&1)^1 for tag == t (dual pollers, selective re-read). All-to-all
// gate unchanged: a block emits tag t+2 only after consuming all tag-(t+1)
// words, which exist only after every block consumed tag t. sbuf race-free:
// sbuf(t+1) writes require passing B1(t+1), which wave 0 reaches only after
// its sbuf(t) read.
__global__ __launch_bounds__(1024) void k_lstm(
    const __hip_bfloat16* __restrict__ xg_f, const __hip_bfloat16* __restrict__ xg_b,
    const float* __restrict__ Whh_f, const float* __restrict__ Whh_b,
    const float* __restrict__ h0, const float* __restrict__ c0v,
    float* __restrict__ hs_f, float* __restrict__ hs_b,
    unsigned* __restrict__ msg, unsigned* __restrict__ abortw)
{
    __shared__ float hbuf[2][HDIM];
    __shared__ unsigned sbuf[16];      // this block's 16 packed words for step t
    __shared__ unsigned sdead;

    int wg = blockIdx.x;
    int dir = wg & 1, slot = wg >> 1;          // slot 0..47
    const __hip_bfloat16* xg = dir ? xg_b : xg_f;
    const float* Whh = dir ? Whh_b : Whh_f;
    float* hs        = dir ? hs_b  : hs_f;
    unsigned* mdir = msg + (size_t)dir * 2 * HDIM;

    int tid = threadIdx.x, lane = tid & 63, wv = tid >> 6;   // wv 0..15
    int q = lane >> 4, gl = lane & 15;
    int j = slot * JPW + wv;

    // this lane's Whh slice: row q*768+j, cols gl*4 + m*64 + e
    float w[48];
    const float* wr = Whh + (size_t)(q * HDIM + j) * HDIM;
    #pragma unroll
    for (int m = 0; m < 12; m++) {
        float4 f4 = *(const float4*)(wr + gl * 4 + m * 64);
        w[m * 4 + 0] = f4.x; w[m * 4 + 1] = f4.y;
        w[m * 4 + 2] = f4.z; w[m * 4 + 3] = f4.w;
    }
    float cst = c0v[dir * HDIM + j];

    if (tid == 0) sdead = 0;

    for (int t = 0; t < SEQ; t++) {
        int xrow = dir ? (SEQ - 1 - t) : t;
        const __hip_bfloat16* xga = xg + (size_t)xrow * G4 + j;
        float xv0 = __bfloat162float(xga[0]);
        float xv1 = __bfloat162float(xga[HDIM]);
        float xv2 = __bfloat162float(xga[2 * HDIM]);
        float xv3 = __bfloat162float(xga[3 * HDIM]);

        int par = (t & 1) ^ 1;   // parity slot holding h(t-1)

        if (wv < 2) {            // dual pollers: wave0 words 0..383, wave1 384..767
            int base = wv * 6;
            if (t == 0) {
                #pragma unroll
                for (int m = 0; m < 6; m++)
                    hbuf[1][(base + m) * 64 + lane] = h0[dir * HDIM + (base + m) * 64 + lane];
            } else {
                const unsigned* g = mdir + (size_t)par * HDIM;
                unsigned vals[6];
                unsigned fresh = 0, rounds = 0;
                bool dead = false;
                for (;;) {
                    #pragma unroll
                    for (int m = 0; m < 6; m++)
                        if (!(fresh & (1u << m)))
                            vals[m] = __hip_atomic_load(&g[(base + m) * 64 + lane],
                                        __ATOMIC_RELAXED, __HIP_MEMORY_SCOPE_AGENT);
                    #pragma unroll
                    for (int m = 0; m < 6; m++)
                        if ((vals[m] >> 16) == (unsigned)t) fresh |= (1u << m);
                    if (__all(fresh == 0x3Fu)) break;
                    unsigned ab = __hip_atomic_load(abortw,
                                    __ATOMIC_RELAXED, __HIP_MEMORY_SCOPE_AGENT);
                    if (ab || ++rounds >= DATA_SPIN) { dead = true; break; }
                }
                #pragma unroll
                for (int m = 0; m < 6; m++) {
                    union { unsigned u; float f; } cvt;
                    cvt.u = (vals[m] & 0xFFFFu) << 16;   // bf16 -> f32 (exact)
                    hbuf[par][(base + m) * 64 + lane] = cvt.f;
                }
                if (dead && lane == 0) {   // cascade shutdown, bounded everywhere
                    __hip_atomic_store(abortw, 1u,
                                       __ATOMIC_RELAXED, __HIP_MEMORY_SCOPE_AGENT);
                    sdead = 1;
                }
            }
        }

        __syncthreads();           // B1: hbuf ready (and sdead visible)
        if (sdead) break;          // block-uniform bail

        // matvec slice over this lane's 48 columns from LDS
        float acc = 0.f;
        #pragma unroll
        for (int m = 0; m < 12; m++) {
            float4 f4 = *(const float4*)&hbuf[par][gl * 4 + m * 64];
            acc += w[m * 4 + 0] * f4.x + w[m * 4 + 1] * f4.y
                 + w[m * 4 + 2] * f4.z + w[m * 4 + 3] * f4.w;
        }
        acc += __shfl_xor(acc, 1);
        acc += __shfl_xor(acc, 2);
        acc += __shfl_xor(acc, 4);
        acc += __shfl_xor(acc, 8);
        float si = __shfl(acc, 0),  sf = __shfl(acc, 16);
        float sg = __shfl(acc, 32), so = __shfl(acc, 48);

        float gi = sigf(xv0 + si), gf = sigf(xv1 + sf);
        float gg = tanhf_fast(xv2 + sg), go = sigf(xv3 + so);
        cst = gf * cst + gi * gg;
        float h = go * tanhf_fast(cst);

        if (lane == 0) {
            union { __hip_bfloat16 b; unsigned short u; } cv;
            cv.b = __float2bfloat16(h);
            sbuf[wv] = ((unsigned)(t + 1) << 16) | (unsigned)cv.u;  // gather in LDS
            int hrow = dir ? (SEQ - 1 - t) : t;
            hs[(size_t)hrow * HDIM + j] = h;          // for K4 (off critical path)
        }
        __syncthreads();           // B2: bounds skew; sbuf complete; hbuf safe

        // ONE coalesced 64B line store for the whole block's 16 words
        if (wv == 0 && lane < 16)
            __hip_atomic_store(&mdir[(size_t)(t & 1) * HDIM + slot * JPW + lane],
                               sbuf[lane],
                               __ATOMIC_RELAXED, __HIP_MEMORY_SCOPE_AGENT);
    }
}

// ---- K4: o = [hs_f,hs_b]@Wc^T + bc, log_softmax; Wc staged in LDS, 16 rows/blk
__global__ __launch_bounds__(256) void k_head(
    const float* __restrict__ hs_f, const float* __restrict__ hs_b,
    const float* __restrict__ Wc, const float* __restrict__ bc,
    float* __restrict__ out)
{
    __shared__ float wcs[CDIM][1536];
    __shared__ float bcs[CDIM];
    int tid = threadIdx.x;
    for (int i = tid; i < CDIM * 1536; i += 256) {
        int n = i / 1536;
        wcs[n][i - n * 1536] = Wc[i];
    }
    if (tid < CDIM) bcs[tid] = bc[tid];
    __syncthreads();

    int lane = tid & 63, wv = tid >> 6;
    int off = (lane < 32) ? lane * 24 : 768 + (lane - 32) * 24;
    for (int rr = 0; rr < 4; rr++) {
        int row = blockIdx.x * 16 + wv * 4 + rr;
        const float* src = (lane < 32) ? (hs_f + (size_t)row * HDIM + lane * 24)
                                       : (hs_b + (size_t)row * HDIM + (lane - 32) * 24);
        float hvv[24];
        #pragma unroll
        for (int k = 0; k < 6; k++) {
            float4 f4 = *(const float4*)(src + k * 4);
            hvv[k * 4 + 0] = f4.x; hvv[k * 4 + 1] = f4.y;
            hvv[k * 4 + 2] = f4.z; hvv[k * 4 + 3] = f4.w;
        }
        float o[CDIM];
        #pragma unroll
        for (int n = 0; n < CDIM; n++) {
            const float* wr2 = &wcs[n][off];
            float s0 = 0.f, s1 = 0.f, s2 = 0.f, s3 = 0.f;
            #pragma unroll
            for (int k = 0; k < 6; k++) {
                float4 w4 = *(const float4*)(wr2 + k * 4);
                s0 += w4.x * hvv[k * 4 + 0];
                s1 += w4.y * hvv[k * 4 + 1];
                s2 += w4.z * hvv[k * 4 + 2];
                s3 += w4.w * hvv[k * 4 + 3];
            }
            o[n] = (s0 + s1) + (s2 + s3);
        }
        #pragma unroll
        for (int n = 0; n < CDIM; n++) {
            #pragma unroll
            for (int d = 1; d < 64; d <<= 1) o[n] += __shfl_xor(o[n], d);
            o[n] += bcs[n];
        }
        float m = o[0];
        #pragma unroll
        for (int n = 1; n < CDIM; n++) m = fmaxf(m, o[n]);
        float sum = 0.f;
        #pragma unroll
        for (int n = 0; n < CDIM; n++) sum += __expf(o[n] - m);
        float ls = m + __logf(sum);
        if (lane == 0) {
            #pragma unroll
            for (int n = 0; n < CDIM; n++) out[(size_t)row * CDIM + n] = o[n] - ls;
        }
    }
}

// ------------------------------------ K5: Viterbi, single wave, shuffle-based
__global__ __launch_bounds__(64) void k_viterbi(
    const float* __restrict__ ts, const float* __restrict__ st,
    const float* __restrict__ en, const float* __restrict__ tr,
    float* __restrict__ tags_out)
{
    __shared__ unsigned char bp[SEQ - 1][16];
    __shared__ unsigned char path[SEQ];
    int n = threadIdx.x;
    bool act = n < CDIM;
    float trn[CDIM];
    #pragma unroll
    for (int p = 0; p < CDIM; p++) trn[p] = act ? tr[p * CDIM + n] : -1e30f;
    float score = act ? (st[n] + ts[n]) : -1e30f;

    for (int s = 1; s < SEQ; s++) {
        float em = act ? ts[(size_t)s * CDIM + n] : 0.f;
        float sp[CDIM];
        #pragma unroll
        for (int p = 0; p < CDIM; p++) sp[p] = __shfl(score, p);
        float best = -1e30f; int arg = 0;
        #pragma unroll
        for (int p = 0; p < CDIM; p++) {
            float v = sp[p] + trn[p];
            if (v > best) { best = v; arg = p; }   // strict > keeps FIRST max
        }
        score = best + em;
        if (act) bp[s - 1][n] = (unsigned char)arg;
    }
    float fin = act ? (score + en[n]) : -1e30f;
    float fv[CDIM];
    #pragma unroll
    for (int p = 0; p < CDIM; p++) fv[p] = __shfl(fin, p);
    __syncthreads();
    if (n == 0) {
        float best = -1e30f; int last = 0;
        #pragma unroll
        for (int p = 0; p < CDIM; p++) { if (fv[p] > best) { best = fv[p]; last = p; } }
        int cur = last;
        path[SEQ - 1] = (unsigned char)cur;
        for (int s = SEQ - 2; s >= 0; s--) { cur = bp[s][cur]; path[s] = (unsigned char)cur; }
    }
    __syncthreads();
    for (int i = n; i < SEQ; i += 64) tags_out[i] = (float)path[i];
}

// --------------------------------------------- fallback if ws is too small
__global__ void k_zero(float* p, int n) {
    int i = blockIdx.x * 256 + threadIdx.x;
    if (i < n) p[i] = 0.f;
}

// ----------------------------------------------------------------- launch
extern "C" void kernel_launch(void* const* d_in, const int* in_sizes, int n_in,
                              void* d_out, int out_size, void* d_ws, size_t ws_size,
                              hipStream_t stream)
{
    const int*   x      = (const int*)d_in[0];
    const int*   casing = (const int*)d_in[1];
    const int*   pos    = (const int*)d_in[2];
    const float* we     = (const float*)d_in[3];
    const float* ce     = (const float*)d_in[4];
    const float* pe     = (const float*)d_in[5];
    const float* Wih_f  = (const float*)d_in[6];
    const float* Whh_f  = (const float*)d_in[7];
    const float* b_f    = (const float*)d_in[8];
    const float* Wih_b  = (const float*)d_in[9];
    const float* Whh_b  = (const float*)d_in[10];
    const float* b_b    = (const float*)d_in[11];
    const float* Wc     = (const float*)d_in[12];
    const float* bc     = (const float*)d_in[13];
    const float* strt   = (const float*)d_in[14];
    const float* endt   = (const float*)d_in[15];
    const float* trans  = (const float*)d_in[16];
    const float* h0     = (const float*)d_in[17];
    const float* c0     = (const float*)d_in[18];

    // ws layout (bytes):
    //   hs_f fp32 6,291,456 @ 0
    //   hs_b fp32 6,291,456 @ 6,291,456
    //   xg_f bf16 12,582,912 @ 12,582,912
    //   xg_b bf16 12,582,912 @ 25,165,824
    //   msg  u32  12,288     @ 37,748,736
    //   abort u32 4          @ 37,761,024
    const size_t need = 37761028;
    if (ws_size < need) {   // clean deterministic failure instead of OOB fault
        k_zero<<<(out_size + 255) / 256, 256, 0, stream>>>((float*)d_out, out_size);
        return;
    }
    char* wsb = (char*)d_ws;
    float* hs_f = (float*)(wsb);
    float* hs_b = (float*)(wsb + 6291456);
    __hip_bfloat16* xg_f = (__hip_bfloat16*)(wsb + 12582912);
    __hip_bfloat16* xg_b = (__hip_bfloat16*)(wsb + 25165824);
    unsigned* msg = (unsigned*)(wsb + 37748736);
    unsigned* abortw = (unsigned*)(wsb + 37761024);

    hipMemsetAsync(msg, 0, 12288 + 4, stream);   // reset tags + abort (replay-safe)

    k_gemm_xg<<<dim3(G4 / 128, SEQ / 128, 2), 256, 0, stream>>>(
        x, casing, pos, we, ce, pe, Wih_f, b_f, Wih_b, b_b, xg_f, xg_b);
    k_lstm<<<2 * NWG, 1024, 0, stream>>>(
        xg_f, xg_b, Whh_f, Whh_b, h0, c0, hs_f, hs_b, msg, abortw);
    k_head<<<SEQ / 16, 256, 0, stream>>>(hs_f, hs_b, Wc, bc, (float*)d_out);
    k_viterbi<<<1, 64, 0, stream>>>(
        (const float*)d_out, strt, endt, trans, (float*)d_out + (size_t)SEQ * CDIM);
}

// Round 14
// 5954.337 us; speedup vs baseline: 1.6268x; 1.0263x over previous
//
#include <hip/hip_runtime.h>
#include <hip/hip_bf16.h>

// BiLSTM-CRF tagger, MI355X. Round 14: resubmit of round-13 (infra flake —
// kernel never reached the device; same signature as rounds 5/6 which passed
// on identical resubmission in round 7).
//   K2 fused embed-gather + xg GEMM via v_mfma_f32_16x16x32_bf16:
//      128x128 tile, 4 waves (2x2), each 64x64 = 4x4 MFMA tiles, K 496->512
//      zero-padded, LDS [128][40] bf16 (80B row stride: 16B-aligned frags,
//      2-way bank aliasing = free). A/B frags: lane l&15 = row/col,
//      (l>>4)*8 = k-offset; D: col=lane&15, row=(lane>>4)*4+reg [verified map].
//   K3 LSTM recurrence: R12 exact (tagged u32 words, parity dbuf, dual
//      pollers, 2 barriers/step, coalesced 64B line store, abort cascade) —
//      frozen at its 5.02 ms structural latency floor.
//   K4 head (Wc in LDS) -> K5 wave-sync Viterbi.

#define SEQ  2048
#define DINW 496
#define HDIM 768
#define G4   3072
#define CDIM 13
#define NWG  48           // workgroups per direction (2*NWG = 96 blocks)
#define JPW  16           // h elements per workgroup (one per wave)
#define DATA_SPIN (1u << 14)
#define LDK  40           // LDS K-stride in bf16 elems (80 B)

typedef __attribute__((ext_vector_type(8))) short bf16x8;   // 8 bf16 (4 VGPR)
typedef __attribute__((ext_vector_type(4))) float f32x4;    // 4 fp32 acc

__device__ __forceinline__ float sigf(float x) { return 1.0f / (1.0f + __expf(-x)); }
__device__ __forceinline__ float tanhf_fast(float x) {
    float ax = fabsf(x);
    float e  = __expf(-2.0f * ax);
    float t  = (1.0f - e) / (1.0f + e);
    return copysignf(t, x);
}
__device__ __forceinline__ unsigned pack_bf16(float a, float b) {
    union { __hip_bfloat16 h; unsigned short u; } x, y;
    x.h = __float2bfloat16(a); y.h = __float2bfloat16(b);
    return (unsigned)x.u | ((unsigned)y.u << 16);
}

// ---- K2: xg = [we[x],ce[casing],pe[pos]] @ Wih^T + b  (bf16 out), MFMA
__global__ __launch_bounds__(256) void k_gemm_xg(
    const int* __restrict__ x, const int* __restrict__ casing, const int* __restrict__ pos,
    const float* __restrict__ we, const float* __restrict__ ce, const float* __restrict__ pe,
    const float* __restrict__ Wih_f, const float* __restrict__ b_f,
    const float* __restrict__ Wih_b, const float* __restrict__ b_b,
    __hip_bfloat16* __restrict__ xg_f, __hip_bfloat16* __restrict__ xg_b)
{
    __shared__ unsigned short Ab[128][LDK];
    __shared__ unsigned short Bb[128][LDK];
    int dir = blockIdx.z;
    const float* B    = dir ? Wih_b : Wih_f;
    const float* bias = dir ? b_b   : b_f;
    __hip_bfloat16* C = dir ? xg_b  : xg_f;
    int n0 = blockIdx.x * 128, m0 = blockIdx.y * 128;
    int tid = threadIdx.x;
    int r = tid & 127, half = tid >> 7;         // staging: row r, k-half
    int lane = tid & 63, wv = tid >> 6;
    int wr = wv >> 1, wc = wv & 1;              // wave -> 64x64 quadrant
    int lrow = lane & 15, kg = lane >> 4;       // frag row/col, k-group

    int m = m0 + r;
    const float* arow_w = we + (size_t)x[m] * 400;
    const float* arow_c = ce + (size_t)casing[m] * 32;
    const float* arow_p = pe + (size_t)pos[m] * 64;
    const float* brow   = B + (size_t)(n0 + r) * DINW;

    f32x4 acc[4][4] = {};

    for (int it = 0; it < 16; it++) {
        int kb = it * 32 + half * 16;           // this thread's 16-elem k-chunk
        float av[16], bv[16];
        if (kb >= DINW) {
            #pragma unroll
            for (int i = 0; i < 16; i++) { av[i] = 0.f; bv[i] = 0.f; }
        } else {
            // region boundaries (400, 432) are multiples of 16: no straddle
            #pragma unroll
            for (int c4 = 0; c4 < 4; c4++) {
                int k = kb + c4 * 4;
                float4 v;
                if (k < 400)      v = *(const float4*)(arow_w + k);
                else if (k < 432) v = *(const float4*)(arow_c + (k - 400));
                else              v = *(const float4*)(arow_p + (k - 432));
                av[c4 * 4 + 0] = v.x; av[c4 * 4 + 1] = v.y;
                av[c4 * 4 + 2] = v.z; av[c4 * 4 + 3] = v.w;
                float4 u = *(const float4*)(brow + k);
                bv[c4 * 4 + 0] = u.x; bv[c4 * 4 + 1] = u.y;
                bv[c4 * 4 + 2] = u.z; bv[c4 * 4 + 3] = u.w;
            }
        }
        unsigned pa[8], pb[8];
        #pragma unroll
        for (int i = 0; i < 8; i++) {
            pa[i] = pack_bf16(av[2 * i], av[2 * i + 1]);
            pb[i] = pack_bf16(bv[2 * i], bv[2 * i + 1]);
        }
        __syncthreads();   // prior iter's frag reads done before overwrite
        uint4* dA = (uint4*)&Ab[r][half * 16];
        uint4* dB = (uint4*)&Bb[r][half * 16];
        dA[0] = make_uint4(pa[0], pa[1], pa[2], pa[3]);
        dA[1] = make_uint4(pa[4], pa[5], pa[6], pa[7]);
        dB[0] = make_uint4(pb[0], pb[1], pb[2], pb[3]);
        dB[1] = make_uint4(pb[4], pb[5], pb[6], pb[7]);
        __syncthreads();   // tiles staged

        union frag { uint4 u; bf16x8 v; };
        frag af[4], bf[4];
        #pragma unroll
        for (int i = 0; i < 4; i++) {
            int arow = wr * 64 + i * 16 + lrow;
            int bcol = wc * 64 + i * 16 + lrow;
            af[i].u = *(const uint4*)((const char*)&Ab[0][0] + arow * (LDK * 2) + kg * 16);
            bf[i].u = *(const uint4*)((const char*)&Bb[0][0] + bcol * (LDK * 2) + kg * 16);
        }
        #pragma unroll
        for (int i = 0; i < 4; i++)
            #pragma unroll
            for (int j = 0; j < 4; j++)
                acc[i][j] = __builtin_amdgcn_mfma_f32_16x16x32_bf16(
                                af[i].v, bf[j].v, acc[i][j], 0, 0, 0);
    }

    // epilogue: D col=lane&15, row=(lane>>4)*4+reg  [m89-verified mapping]
    #pragma unroll
    for (int j = 0; j < 4; j++) {
        int col = n0 + wc * 64 + j * 16 + lrow;
        float bsv = bias[col];
        #pragma unroll
        for (int i = 0; i < 4; i++) {
            int rbase = m0 + wr * 64 + i * 16 + kg * 4;
            #pragma unroll
            for (int reg = 0; reg < 4; reg++)
                C[(size_t)(rbase + reg) * G4 + col] =
                    __float2bfloat16(acc[i][j][reg] + bsv);
        }
    }
}

// ------------------------------------------------------- K3: LSTM recurrence
// R12 exact (proven 5.02 ms). msg[dir][parity][768] u32 {tag<<16|bf16 h}; block
// slot owns words slot*16..+15 (one 64B line), gathered in LDS, issued after B2
// as one coalesced line store. Dual pollers, selective re-read, all-to-all gate.
__global__ __launch_bounds__(1024) void k_lstm(
    const __hip_bfloat16* __restrict__ xg_f, const __hip_bfloat16* __restrict__ xg_b,
    const float* __restrict__ Whh_f, const float* __restrict__ Whh_b,
    const float* __restrict__ h0, const float* __restrict__ c0v,
    float* __restrict__ hs_f, float* __restrict__ hs_b,
    unsigned* __restrict__ msg, unsigned* __restrict__ abortw)
{
    __shared__ float hbuf[2][HDIM];
    __shared__ unsigned sbuf[16];
    __shared__ unsigned sdead;

    int wg = blockIdx.x;
    int dir = wg & 1, slot = wg >> 1;
    const __hip_bfloat16* xg = dir ? xg_b : xg_f;
    const float* Whh = dir ? Whh_b : Whh_f;
    float* hs        = dir ? hs_b  : hs_f;
    unsigned* mdir = msg + (size_t)dir * 2 * HDIM;

    int tid = threadIdx.x, lane = tid & 63, wv = tid >> 6;
    int q = lane >> 4, gl = lane & 15;
    int j = slot * JPW + wv;

    float w[48];
    const float* wr = Whh + (size_t)(q * HDIM + j) * HDIM;
    #pragma unroll
    for (int m = 0; m < 12; m++) {
        float4 f4 = *(const float4*)(wr + gl * 4 + m * 64);
        w[m * 4 + 0] = f4.x; w[m * 4 + 1] = f4.y;
        w[m * 4 + 2] = f4.z; w[m * 4 + 3] = f4.w;
    }
    float cst = c0v[dir * HDIM + j];

    if (tid == 0) sdead = 0;

    for (int t = 0; t < SEQ; t++) {
        int xrow = dir ? (SEQ - 1 - t) : t;
        const __hip_bfloat16* xga = xg + (size_t)xrow * G4 + j;
        float xv0 = __bfloat162float(xga[0]);
        float xv1 = __bfloat162float(xga[HDIM]);
        float xv2 = __bfloat162float(xga[2 * HDIM]);
        float xv3 = __bfloat162float(xga[3 * HDIM]);

        int par = (t & 1) ^ 1;

        if (wv < 2) {
            int base = wv * 6;
            if (t == 0) {
                #pragma unroll
                for (int m = 0; m < 6; m++)
                    hbuf[1][(base + m) * 64 + lane] = h0[dir * HDIM + (base + m) * 64 + lane];
            } else {
                const unsigned* g = mdir + (size_t)par * HDIM;
                unsigned vals[6];
                unsigned fresh = 0, rounds = 0;
                bool dead = false;
                for (;;) {
                    #pragma unroll
                    for (int m = 0; m < 6; m++)
                        if (!(fresh & (1u << m)))
                            vals[m] = __hip_atomic_load(&g[(base + m) * 64 + lane],
                                        __ATOMIC_RELAXED, __HIP_MEMORY_SCOPE_AGENT);
                    #pragma unroll
                    for (int m = 0; m < 6; m++)
                        if ((vals[m] >> 16) == (unsigned)t) fresh |= (1u << m);
                    if (__all(fresh == 0x3Fu)) break;
                    unsigned ab = __hip_atomic_load(abortw,
                                    __ATOMIC_RELAXED, __HIP_MEMORY_SCOPE_AGENT);
                    if (ab || ++rounds >= DATA_SPIN) { dead = true; break; }
                }
                #pragma unroll
                for (int m = 0; m < 6; m++) {
                    union { unsigned u; float f; } cvt;
                    cvt.u = (vals[m] & 0xFFFFu) << 16;
                    hbuf[par][(base + m) * 64 + lane] = cvt.f;
                }
                if (dead && lane == 0) {
                    __hip_atomic_store(abortw, 1u,
                                       __ATOMIC_RELAXED, __HIP_MEMORY_SCOPE_AGENT);
                    sdead = 1;
                }
            }
        }

        __syncthreads();           // B1
        if (sdead) break;

        float acc = 0.f;
        #pragma unroll
        for (int m = 0; m < 12; m++) {
            float4 f4 = *(const float4*)&hbuf[par][gl * 4 + m * 64];
            acc += w[m * 4 + 0] * f4.x + w[m * 4 + 1] * f4.y
                 + w[m * 4 + 2] * f4.z + w[m * 4 + 3] * f4.w;
        }
        acc += __shfl_xor(acc, 1);
        acc += __shfl_xor(acc, 2);
        acc += __shfl_xor(acc, 4);
        acc += __shfl_xor(acc, 8);
        float si = __shfl(acc, 0),  sf = __shfl(acc, 16);
        float sg = __shfl(acc, 32), so = __shfl(acc, 48);

        float gi = sigf(xv0 + si), gf = sigf(xv1 + sf);
        float gg = tanhf_fast(xv2 + sg), go = sigf(xv3 + so);
        cst = gf * cst + gi * gg;
        float h = go * tanhf_fast(cst);

        if (lane == 0) {
            union { __hip_bfloat16 b; unsigned short u; } cv;
            cv.b = __float2bfloat16(h);
            sbuf[wv] = ((unsigned)(t + 1) << 16) | (unsigned)cv.u;
            int hrow = dir ? (SEQ - 1 - t) : t;
            hs[(size_t)hrow * HDIM + j] = h;
        }
        __syncthreads();           // B2

        if (wv == 0 && lane < 16)
            __hip_atomic_store(&mdir[(size_t)(t & 1) * HDIM + slot * JPW + lane],
                               sbuf[lane],
                               __ATOMIC_RELAXED, __HIP_MEMORY_SCOPE_AGENT);
    }
}

// ---- K4: o = [hs_f,hs_b]@Wc^T + bc, log_softmax; Wc staged in LDS, 16 rows/blk
__global__ __launch_bounds__(256) void k_head(
    const float* __restrict__ hs_f, const float* __restrict__ hs_b,
    const float* __restrict__ Wc, const float* __restrict__ bc,
    float* __restrict__ out)
{
    __shared__ float wcs[CDIM][1536];
    __shared__ float bcs[CDIM];
    int tid = threadIdx.x;
    for (int i = tid; i < CDIM * 1536; i += 256) {
        int n = i / 1536;
        wcs[n][i - n * 1536] = Wc[i];
    }
    if (tid < CDIM) bcs[tid] = bc[tid];
    __syncthreads();

    int lane = tid & 63, wv = tid >> 6;
    int off = (lane < 32) ? lane * 24 : 768 + (lane - 32) * 24;
    for (int rr = 0; rr < 4; rr++) {
        int row = blockIdx.x * 16 + wv * 4 + rr;
        const float* src = (lane < 32) ? (hs_f + (size_t)row * HDIM + lane * 24)
                                       : (hs_b + (size_t)row * HDIM + (lane - 32) * 24);
        float hvv[24];
        #pragma unroll
        for (int k = 0; k < 6; k++) {
            float4 f4 = *(const float4*)(src + k * 4);
            hvv[k * 4 + 0] = f4.x; hvv[k * 4 + 1] = f4.y;
            hvv[k * 4 + 2] = f4.z; hvv[k * 4 + 3] = f4.w;
        }
        float o[CDIM];
        #pragma unroll
        for (int n = 0; n < CDIM; n++) {
            const float* wr2 = &wcs[n][off];
            float s0 = 0.f, s1 = 0.f, s2 = 0.f, s3 = 0.f;
            #pragma unroll
            for (int k = 0; k < 6; k++) {
                float4 w4 = *(const float4*)(wr2 + k * 4);
                s0 += w4.x * hvv[k * 4 + 0];
                s1 += w4.y * hvv[k * 4 + 1];
                s2 += w4.z * hvv[k * 4 + 2];
                s3 += w4.w * hvv[k * 4 + 3];
            }
            o[n] = (s0 + s1) + (s2 + s3);
        }
        #pragma unroll
        for (int n = 0; n < CDIM; n++) {
            #pragma unroll
            for (int d = 1; d < 64; d <<= 1) o[n] += __shfl_xor(o[n], d);
            o[n] += bcs[n];
        }
        float m = o[0];
        #pragma unroll
        for (int n = 1; n < CDIM; n++) m = fmaxf(m, o[n]);
        float sum = 0.f;
        #pragma unroll
        for (int n = 0; n < CDIM; n++) sum += __expf(o[n] - m);
        float ls = m + __logf(sum);
        if (lane == 0) {
            #pragma unroll
            for (int n = 0; n < CDIM; n++) out[(size_t)row * CDIM + n] = o[n] - ls;
        }
    }
}

// ------------------------------------ K5: Viterbi, single wave, shuffle-based
__global__ __launch_bounds__(64) void k_viterbi(
    const float* __restrict__ ts, const float* __restrict__ st,
    const float* __restrict__ en, const float* __restrict__ tr,
    float* __restrict__ tags_out)
{
    __shared__ unsigned char bp[SEQ - 1][16];
    __shared__ unsigned char path[SEQ];
    int n = threadIdx.x;
    bool act = n < CDIM;
    float trn[CDIM];
    #pragma unroll
    for (int p = 0; p < CDIM; p++) trn[p] = act ? tr[p * CDIM + n] : -1e30f;
    float score = act ? (st[n] + ts[n]) : -1e30f;

    for (int s = 1; s < SEQ; s++) {
        float em = act ? ts[(size_t)s * CDIM + n] : 0.f;
        float sp[CDIM];
        #pragma unroll
        for (int p = 0; p < CDIM; p++) sp[p] = __shfl(score, p);
        float best = -1e30f; int arg = 0;
        #pragma unroll
        for (int p = 0; p < CDIM; p++) {
            float v = sp[p] + trn[p];
            if (v > best) { best = v; arg = p; }   // strict > keeps FIRST max
        }
        score = best + em;
        if (act) bp[s - 1][n] = (unsigned char)arg;
    }
    float fin = act ? (score + en[n]) : -1e30f;
    float fv[CDIM];
    #pragma unroll
    for (int p = 0; p < CDIM; p++) fv[p] = __shfl(fin, p);
    __syncthreads();
    if (n == 0) {
        float best = -1e30f; int last = 0;
        #pragma unroll
        for (int p = 0; p < CDIM; p++) { if (fv[p] > best) { best = fv[p]; last = p; } }
        int cur = last;
        path[SEQ - 1] = (unsigned char)cur;
        for (int s = SEQ - 2; s >= 0; s--) { cur = bp[s][cur]; path[s] = (unsigned char)cur; }
    }
    __syncthreads();
    for (int i = n; i < SEQ; i += 64) tags_out[i] = (float)path[i];
}

// --------------------------------------------- fallback if ws is too small
__global__ void k_zero(float* p, int n) {
    int i = blockIdx.x * 256 + threadIdx.x;
    if (i < n) p[i] = 0.f;
}

// ----------------------------------------------------------------- launch
extern "C" void kernel_launch(void* const* d_in, const int* in_sizes, int n_in,
                              void* d_out, int out_size, void* d_ws, size_t ws_size,
                              hipStream_t stream)
{
    const int*   x      = (const int*)d_in[0];
    const int*   casing = (const int*)d_in[1];
    const int*   pos    = (const int*)d_in[2];
    const float* we     = (const float*)d_in[3];
    const float* ce     = (const float*)d_in[4];
    const float* pe     = (const float*)d_in[5];
    const float* Wih_f  = (const float*)d_in[6];
    const float* Whh_f  = (const float*)d_in[7];
    const float* b_f    = (const float*)d_in[8];
    const float* Wih_b  = (const float*)d_in[9];
    const float* Whh_b  = (const float*)d_in[10];
    const float* b_b    = (const float*)d_in[11];
    const float* Wc     = (const float*)d_in[12];
    const float* bc     = (const float*)d_in[13];
    const float* strt   = (const float*)d_in[14];
    const float* endt   = (const float*)d_in[15];
    const float* trans  = (const float*)d_in[16];
    const float* h0     = (const float*)d_in[17];
    const float* c0     = (const float*)d_in[18];

    // ws layout (bytes):
    //   hs_f fp32 6,291,456 @ 0
    //   hs_b fp32 6,291,456 @ 6,291,456
    //   xg_f bf16 12,582,912 @ 12,582,912
    //   xg_b bf16 12,582,912 @ 25,165,824
    //   msg  u32  12,288     @ 37,748,736
    //   abort u32 4          @ 37,761,024
    const size_t need = 37761028;
    if (ws_size < need) {   // clean deterministic failure instead of OOB fault
        k_zero<<<(out_size + 255) / 256, 256, 0, stream>>>((float*)d_out, out_size);
        return;
    }
    char* wsb = (char*)d_ws;
    float* hs_f = (float*)(wsb);
    float* hs_b = (float*)(wsb + 6291456);
    __hip_bfloat16* xg_f = (__hip_bfloat16*)(wsb + 12582912);
    __hip_bfloat16* xg_b = (__hip_bfloat16*)(wsb + 25165824);
    unsigned* msg = (unsigned*)(wsb + 37748736);
    unsigned* abortw = (unsigned*)(wsb + 37761024);

    hipMemsetAsync(msg, 0, 12288 + 4, stream);   // reset tags + abort (replay-safe)

    k_gemm_xg<<<dim3(G4 / 128, SEQ / 128, 2), 256, 0, stream>>>(
        x, casing, pos, we, ce, pe, Wih_f, b_f, Wih_b, b_b, xg_f, xg_b);
    k_lstm<<<2 * NWG, 1024, 0, stream>>>(
        xg_f, xg_b, Whh_f, Whh_b, h0, c0, hs_f, hs_b, msg, abortw);
    k_head<<<SEQ / 16, 256, 0, stream>>>(hs_f, hs_b, Wc, bc, (float*)d_out);
    k_viterbi<<<1, 64, 0, stream>>>(
        (const float*)d_out, strt, endt, trans, (float*)d_out + (size_t)SEQ * CDIM);
}